// Round 2
// baseline (69.908 us; speedup 1.0000x reference)
//
#include <hip/hip_runtime.h>
#include <math.h>
#include <stdint.h>

#define N_AGENTS 2048
#define R_CAND   128
#define NUM_MODS 6
#define T_STEPS  30
#define B_BATCH  16

// out layout: [0]=cls_loss, [1]=reg_loss, [2..5761]=traj_eval(16,6,30,2), [5762]=num_cls, [5763]=num_reg

__global__ __launch_bounds__(128) void agent_kernel(
    const float* __restrict__ roi,      // [N*R,5]  (logit, dx, dy, d2, d3)
    const float* __restrict__ anchor,   // [N*R,4]
    const float* __restrict__ ctrs,     // [N,2]
    const float* __restrict__ feats,    // [N,20,3]
    const float* __restrict__ gt,       // [N,T,2]
    const int* __restrict__ has,        // [N,T] bool -> int32 on upload
    const int* __restrict__ natgs,      // [B]
    float* __restrict__ out,
    double* __restrict__ part)          // [N,4] cls,reg,ncls,nreg
{
#pragma clang fp contract(off)
    const int a   = blockIdx.x;
    const int tid = threadIdx.x;

    __shared__ float  s_logic[R_CAND];
    __shared__ double s_gx[R_CAND], s_gy[R_CAND], s_g2[R_CAND], s_g3[R_CAND];
    __shared__ double s_sx[R_CAND], s_sy[R_CAND];   // sorted by logit desc
    __shared__ int    s_sidx[R_CAND];               // sorted pos -> orig idx
    __shared__ double s_rd[R_CAND];  __shared__ int s_ri[R_CAND];   // selection master
    __shared__ double w_d[R_CAND];   __shared__ int w_i[R_CAND];    // reduce scratch
    __shared__ int    s_sup, s_cnt;
    __shared__ float  s_slog[NUM_MODS];
    __shared__ double s_sel[NUM_MODS][4];
    __shared__ double s_coef[NUM_MODS][6];
    __shared__ double s_traj[NUM_MODS][T_STEPS][2];

    // ---- 1. load candidates, goals = anchor + pred[:,1:]
    {
        const float* rp  = roi    + (size_t)(a * R_CAND + tid) * 5;
        const float* apr = anchor + (size_t)(a * R_CAND + tid) * 4;
        s_logic[tid] = rp[0];
        s_gx[tid] = (double)apr[0] + (double)rp[1];
        s_gy[tid] = (double)apr[1] + (double)rp[2];
        s_g2[tid] = (double)apr[2] + (double)rp[3];
        s_g3[tid] = (double)apr[3] + (double)rp[4];
    }
    __syncthreads();

    // ---- 2. rank = stable argsort(-logic) position
    {
        const float lr = s_logic[tid];
        int rank = 0;
        for (int j = 0; j < R_CAND; ++j) {
            const float lj = s_logic[j];
            rank += (lj > lr) || (lj == lr && j < tid);
        }
        s_sidx[rank] = tid;
        s_sx[rank]   = s_gx[tid];
        s_sy[rank]   = s_gy[tid];
    }
    __syncthreads();

    // ---- 3. greedy NMS in sorted order (keep flag per thread = sorted pos tid)
    int k = 1;
    const double xj = s_sx[tid], yj = s_sy[tid];
    for (int i = 1; i < R_CAND; ++i) {
        if (tid == 0) s_sup = 0;
        __syncthreads();
        if (tid < i && k) {
            const double xi = s_sx[i], yi = s_sy[i];
            if (fabs(xj - xi) < 0.51 && fabs(yj - yi) < 0.51) {
                // replicate reference box/IoU arithmetic exactly (f64, no contraction)
                const double jx1 = xj - 0.25, jy1 = yj - 0.25, jx2 = xj + 0.25, jy2 = yj + 0.25;
                const double ix1 = xi - 0.25, iy1 = yi - 0.25, ix2 = xi + 0.25, iy2 = yi + 0.25;
                const double areaj = (jx2 - jx1) * (jy2 - jy1);
                const double areai = (ix2 - ix1) * (iy2 - iy1);
                const double ltx = fmax(jx1, ix1), lty = fmax(jy1, iy1);
                const double rbx = fmin(jx2, ix2), rby = fmin(jy2, iy2);
                const double ww = fmax(rbx - ltx, 0.0), hh = fmax(rby - lty, 0.0);
                const double inter = ww * hh;
                const double iou = inter / (areaj + areai - inter);
                if (iou > 0.5) s_sup = 1;
            }
        }
        __syncthreads();
        if (tid == i) k = (s_sup == 0);
        __syncthreads();
    }

    if (tid == 0) s_cnt = 0;
    __syncthreads();
    if (k) atomicAdd(&s_cnt, 1);
    __syncthreads();
    const int kf = (s_cnt >= NUM_MODS) ? k : 1;

    // ---- 4. dist to gt endpoint, top-6 (stable: key = (dist, orig idx))
    {
        const double gtx = gt[((size_t)a * T_STEPS + (T_STEPS - 1)) * 2 + 0];
        const double gty = gt[((size_t)a * T_STEPS + (T_STEPS - 1)) * 2 + 1];
        s_rd[tid] = kf ? (fabs(s_sx[tid] - gtx) + fabs(s_sy[tid] - gty)) : INFINITY;
        s_ri[tid] = s_sidx[tid];
    }
    __syncthreads();

    for (int m = 0; m < NUM_MODS; ++m) {
        w_d[tid] = s_rd[tid]; w_i[tid] = s_ri[tid];
        __syncthreads();
        for (int off = 64; off >= 1; off >>= 1) {
            if (tid < off) {
                const double d2 = w_d[tid + off]; const int i2 = w_i[tid + off];
                const double d1 = w_d[tid];       const int i1 = w_i[tid];
                if (d2 < d1 || (d2 == d1 && i2 < i1)) { w_d[tid] = d2; w_i[tid] = i2; }
            }
            __syncthreads();
        }
        const int win = w_i[0];
        if (tid == 0) {
            s_slog[m]   = s_logic[win];
            s_sel[m][0] = s_gx[win]; s_sel[m][1] = s_gy[win];
            s_sel[m][2] = s_g2[win]; s_sel[m][3] = s_g3[win];
        }
        if (s_ri[tid] == win) { s_rd[tid] = INFINITY; s_ri[tid] = 0x7fffffff; }
        __syncthreads();
    }

    // ---- 5. quadratic coefficients + trajectories
    const double ap0 = ctrs[(size_t)a * 2 + 0];
    const double ap1 = ctrs[(size_t)a * 2 + 1];
    const double ap2 = feats[((size_t)a * 20 + 19) * 3 + 0];
    const double ap3 = feats[((size_t)a * 20 + 19) * 3 + 1];
    if (tid < NUM_MODS) {
        const int m = tid;
        const double sel0 = s_sel[m][0], sel1 = s_sel[m][1];
        const double sel2 = s_sel[m][2], sel3 = s_sel[m][3];
        const double a1c = (2.0 * sel0 * ap2 + 2.0 * ap0 * ap2) / (2.0 + ap2 - sel2);
        const double a0c = sel0 - ap0 - a1c;
        const double b1c = (2.0 * sel1 * ap3 + 2.0 * ap1 * ap3) / (2.0 + ap3 - sel3);
        const double b0c = sel1 - ap1 - b1c;
        s_coef[m][0] = a0c; s_coef[m][1] = a1c; s_coef[m][2] = ap0;
        s_coef[m][3] = b0c; s_coef[m][4] = b1c; s_coef[m][5] = ap1;
    }
    __syncthreads();
    for (int p = tid; p < NUM_MODS * T_STEPS; p += 128) {
        const int m = p / T_STEPS, t = p % T_STEPS;
        const float sf = (float)t / (float)(T_STEPS - 1);   // ref: arange(T, f32)/(T-1)
        const float s2f = sf * sf;
        const double s1 = (double)sf, s2 = (double)s2f;
        s_traj[m][t][0] = s_coef[m][0] * s2 + s_coef[m][1] * s1 + s_coef[m][2];
        s_traj[m][t][1] = s_coef[m][3] * s2 + s_coef[m][4] * s1 + s_coef[m][5];
    }
    __syncthreads();

    // ---- 6. losses (thread 0, serial — tiny)
    if (tid == 0) {
        double best = -1e300; int lt = 0;
        for (int t = 0; t < T_STEPS; ++t) {
            const double h = has[(size_t)a * T_STEPS + t] ? 1.0 : 0.0;
            const double v = h + (0.1 * (double)t) / (double)T_STEPS;
            if (v > best) { best = v; lt = t; }
        }
        const int mask = (best > 1.0);
        const double egx = gt[((size_t)a * T_STEPS + lt) * 2 + 0];
        const double egy = gt[((size_t)a * T_STEPS + lt) * 2 + 1];
        double bd = 1e300; int mi = 0;
        for (int m = 0; m < NUM_MODS; ++m) {
            const double dx = s_traj[m][lt][0] - egx;
            const double dy = s_traj[m][lt][1] - egy;
            const double d = sqrt(dx * dx + dy * dy);
            if (d < bd) { bd = d; mi = m; }
        }
        double cls = 0.0;
        for (int m = 0; m < NUM_MODS; ++m) {
            const double l = (double)s_slog[m];
            const double g = (m == mi) ? 1.0 : 0.0;
            cls += fmax(l, 0.0) - l * g + log1p(exp(-fabs(l)));
        }
        if (!mask) cls = 0.0;
        double reg = 0.0; int nreg = 0;
        for (int t = 0; t < T_STEPS; ++t) {
            const int hw = mask && (has[(size_t)a * T_STEPS + t] != 0);
            if (hw) {
                ++nreg;
                for (int c = 0; c < 2; ++c) {
                    const double diff = s_traj[mi][t][c] - gt[((size_t)a * T_STEPS + t) * 2 + c];
                    const double ad = fabs(diff);
                    reg += (ad < 1.0) ? 0.5 * diff * diff : (ad - 0.5);
                }
            }
        }
        part[(size_t)a * 4 + 0] = cls;
        part[(size_t)a * 4 + 1] = reg;
        part[(size_t)a * 4 + 2] = mask ? 1.0 : 0.0;
        part[(size_t)a * 4 + 3] = (double)nreg;
    }
    __syncthreads();

    // ---- 7. traj_eval gather (note: temp is NOT cumsum — [0, natgs[0], natgs[1], ...])
    const double* tp = &s_traj[0][0][0];
    for (int b = 0; b < B_BATCH; ++b) {
        const int target = (b == 0) ? 0 : natgs[b - 1];
        if (target == a) {
            for (int p = tid; p < NUM_MODS * T_STEPS * 2; p += 128)
                out[2 + (size_t)b * NUM_MODS * T_STEPS * 2 + p] = (float)tp[p];
        }
    }
}

__global__ __launch_bounds__(256) void reduce_kernel(
    const double* __restrict__ part, float* __restrict__ out)
{
    __shared__ double s0[256], s1[256], s2[256], s3[256];
    const int tid = threadIdx.x;
    double c = 0, r = 0, n = 0, w = 0;
    for (int a = tid; a < N_AGENTS; a += 256) {
        c += part[(size_t)a * 4 + 0];
        r += part[(size_t)a * 4 + 1];
        n += part[(size_t)a * 4 + 2];
        w += part[(size_t)a * 4 + 3];
    }
    s0[tid] = c; s1[tid] = r; s2[tid] = n; s3[tid] = w;
    __syncthreads();
    for (int off = 128; off >= 1; off >>= 1) {
        if (tid < off) {
            s0[tid] += s0[tid + off]; s1[tid] += s1[tid + off];
            s2[tid] += s2[tid + off]; s3[tid] += s3[tid + off];
        }
        __syncthreads();
    }
    if (tid == 0) {
        out[0]    = (float)s0[0];
        out[1]    = (float)s1[0];
        out[5762] = (float)s2[0];
        out[5763] = (float)s3[0];
    }
}

extern "C" void kernel_launch(void* const* d_in, const int* in_sizes, int n_in,
                              void* d_out, int out_size, void* d_ws, size_t ws_size,
                              hipStream_t stream) {
    const float*   roi    = (const float*)d_in[0];
    const float*   anchor = (const float*)d_in[1];
    const float*   ctrs   = (const float*)d_in[2];
    const float*   feats  = (const float*)d_in[3];
    const float*   gt     = (const float*)d_in[4];
    const int*     has    = (const int*)d_in[5];
    const int*     natgs  = (const int*)d_in[6];
    float*  out  = (float*)d_out;
    double* part = (double*)d_ws;   // 2048*4 doubles = 64 KB

    agent_kernel<<<N_AGENTS, 128, 0, stream>>>(roi, anchor, ctrs, feats, gt, has, natgs, out, part);
    reduce_kernel<<<1, 256, 0, stream>>>(part, out);
}

// Round 4
// 47.861 us; speedup vs baseline: 1.4606x; 1.4606x over previous
//
#include <hip/hip_runtime.h>
#include <math.h>
#include <stdint.h>

#define N_AGENTS 2048
#define R_CAND   128
#define NUM_MODS 6
#define T_STEPS  30
#define B_BATCH  16

// out layout: [0]=cls_loss, [1]=reg_loss, [2..5761]=traj_eval(16,6,30,2), [5762]=num_cls, [5763]=num_reg

__global__ __launch_bounds__(128) void agent_kernel(
    const float* __restrict__ roi,      // [N*R,5]  (logit, dx, dy, d2, d3)
    const float* __restrict__ anchor,   // [N*R,4]
    const float* __restrict__ ctrs,     // [N,2]
    const float* __restrict__ feats,    // [N,20,3]
    const float* __restrict__ gt,       // [N,T,2]
    const int* __restrict__ has,        // [N,T] bool -> int32
    const int* __restrict__ natgs,      // [B]
    float* __restrict__ out,
    double* __restrict__ part)          // [N,4] cls,reg,ncls,nreg
{
#pragma clang fp contract(off)
    const int a   = blockIdx.x;
    const int tid = threadIdx.x;

    __shared__ float    s_logic[R_CAND];                  // orig order
    __shared__ double   s_gx[R_CAND], s_gy[R_CAND], s_g2[R_CAND], s_g3[R_CAND]; // orig order
    __shared__ double   s_sx[R_CAND], s_sy[R_CAND];       // sorted by logit desc (f64)
    __shared__ float    s_fx[R_CAND], s_fy[R_CAND];       // sorted, f32 copies for prefilter
    __shared__ int      s_sidx[R_CAND];                   // sorted pos -> orig idx
    __shared__ uint64_t s_row[R_CAND][2];                 // suppression rows (bits j>i)
    __shared__ double   s_d[R_CAND];  __shared__ int s_i[R_CAND];
    __shared__ double   s_gtrow[T_STEPS * 2];             // gt row (f64)
    __shared__ int      s_has[T_STEPS];
    __shared__ int      s_win[NUM_MODS];
    __shared__ float    s_slog[NUM_MODS];
    __shared__ double   s_coef[NUM_MODS][6];
    __shared__ double   s_traj[NUM_MODS][T_STEPS][2];
    __shared__ double   s_red[66];
    __shared__ int      s_lt, s_mi, s_mask;

    // ---- 1. load candidates + per-agent rows
    {
        const float* rp  = roi    + (size_t)(a * R_CAND + tid) * 5;
        const float* apr = anchor + (size_t)(a * R_CAND + tid) * 4;
        s_logic[tid] = rp[0];
        s_gx[tid] = (double)apr[0] + (double)rp[1];
        s_gy[tid] = (double)apr[1] + (double)rp[2];
        s_g2[tid] = (double)apr[2] + (double)rp[3];
        s_g3[tid] = (double)apr[3] + (double)rp[4];
    }
    if (tid < T_STEPS * 2) s_gtrow[tid] = (double)gt[(size_t)a * T_STEPS * 2 + tid];
    if (tid >= 64 && tid < 64 + T_STEPS) s_has[tid - 64] = has[(size_t)a * T_STEPS + (tid - 64)];
    __syncthreads();

    // ---- 2. rank = stable argsort(-logic) position
    {
        const float lr = s_logic[tid];
        int rank = 0;
        for (int j = 0; j < R_CAND; ++j) {
            const float lj = s_logic[j];
            rank += (lj > lr) || (lj == lr && j < tid);
        }
        s_sidx[rank] = tid;
        s_sx[rank]   = s_gx[tid];
        s_sy[rank]   = s_gy[tid];
        s_fx[rank]   = (float)s_gx[tid];
        s_fy[rank]   = (float)s_gy[tid];
    }
    __syncthreads();

    // ---- 3a. suppression rows: bit j set iff j>i and iou(i,j)>0.5 (exact f64 confirm)
    {
        const int i = tid;
        const float  fxi = s_fx[i], fyi = s_fy[i];
        const double xi  = s_sx[i], yi  = s_sy[i];
        uint64_t r0 = 0, r1 = 0;
        for (int j = i + 1; j < R_CAND; ++j) {
            // cheap f32 prefilter: iou>0.5 for 0.5x0.5 boxes requires |dx|,|dy| < 1/6
            const float dxf = fabsf(fxi - s_fx[j]);
            const float dyf = fabsf(fyi - s_fy[j]);
            if (dxf < 0.17f && dyf < 0.17f) {
                const double xj = s_sx[j], yj = s_sy[j];
                const double ix1 = xi - 0.25, iy1 = yi - 0.25, ix2 = xi + 0.25, iy2 = yi + 0.25;
                const double jx1 = xj - 0.25, jy1 = yj - 0.25, jx2 = xj + 0.25, jy2 = yj + 0.25;
                const double areai = (ix2 - ix1) * (iy2 - iy1);
                const double areaj = (jx2 - jx1) * (jy2 - jy1);
                const double ltx = fmax(ix1, jx1), lty = fmax(iy1, jy1);
                const double rbx = fmin(ix2, jx2), rby = fmin(iy2, jy2);
                const double ww = fmax(rbx - ltx, 0.0), hh = fmax(rby - lty, 0.0);
                const double inter = ww * hh;
                const double iou = inter / (areai + areaj - inter);
                if (iou > 0.5) {
                    if (j < 64) r0 |= (1ull << j);
                    else        r1 |= (1ull << (j - 64));
                }
            }
        }
        s_row[i][0] = r0;
        s_row[i][1] = r1;
    }
    __syncthreads();

    // ---- 3b. greedy scan (redundant in all threads; LDS broadcast reads, no barriers)
    uint64_t keep0 = ~0ull, keep1 = ~0ull;
    for (int i = 0; i < 64; ++i) {
        if ((keep0 >> i) & 1ull) {
            keep0 &= ~s_row[i][0];
            keep1 &= ~s_row[i][1];
        }
    }
    for (int i = 0; i < 64; ++i) {
        if ((keep1 >> i) & 1ull) {
            keep1 &= ~s_row[64 + i][1];   // rows i>=64 have word0 == 0
        }
    }
    const int kcnt  = __popcll(keep0) + __popcll(keep1);
    const int kfall = (kcnt < NUM_MODS);   // keep everything if fewer than 6 survive

    // ---- 4. dist to gt endpoint (f64), stable top-6 by (dist, orig idx)
    {
        const double gtx = s_gtrow[(T_STEPS - 1) * 2 + 0];
        const double gty = s_gtrow[(T_STEPS - 1) * 2 + 1];
        const int keptbit = (tid < 64) ? (int)((keep0 >> tid) & 1ull)
                                       : (int)((keep1 >> (tid - 64)) & 1ull);
        const int kept = kfall ? 1 : keptbit;
        s_d[tid] = kept ? (fabs(s_sx[tid] - gtx) + fabs(s_sy[tid] - gty)) : INFINITY;
        s_i[tid] = s_sidx[tid];
    }
    __syncthreads();

    if (tid < 64) {
        double d_lo = s_d[tid],      d_hi = s_d[tid + 64];
        int    i_lo = s_i[tid],      i_hi = s_i[tid + 64];
        for (int m = 0; m < NUM_MODS; ++m) {
            double bd; int bi;
            if (d_lo < d_hi || (d_lo == d_hi && i_lo < i_hi)) { bd = d_lo; bi = i_lo; }
            else                                               { bd = d_hi; bi = i_hi; }
            for (int off = 32; off >= 1; off >>= 1) {
                const double od = __shfl_down(bd, (unsigned)off, 64);
                const int    oi = __shfl_down(bi, (unsigned)off, 64);
                if (od < bd || (od == bd && oi < bi)) { bd = od; bi = oi; }
            }
            bi = __shfl(bi, 0, 64);
            if (tid == 0) s_win[m] = bi;
            if (i_lo == bi) d_lo = INFINITY;
            if (i_hi == bi) d_hi = INFINITY;
        }
    }
    __syncthreads();

    // ---- 5. coefficients (tid<6) + trajectories
    if (tid < NUM_MODS) {
        const int m = tid, win = s_win[m];
        const double ap0 = ctrs[(size_t)a * 2 + 0];
        const double ap1 = ctrs[(size_t)a * 2 + 1];
        const double ap2 = feats[((size_t)a * 20 + 19) * 3 + 0];
        const double ap3 = feats[((size_t)a * 20 + 19) * 3 + 1];
        const double sel0 = s_gx[win], sel1 = s_gy[win];
        const double sel2 = s_g2[win], sel3 = s_g3[win];
        s_slog[m] = s_logic[win];
        const double a1c = (2.0 * sel0 * ap2 + 2.0 * ap0 * ap2) / (2.0 + ap2 - sel2);
        const double a0c = sel0 - ap0 - a1c;
        const double b1c = (2.0 * sel1 * ap3 + 2.0 * ap1 * ap3) / (2.0 + ap3 - sel3);
        const double b0c = sel1 - ap1 - b1c;
        s_coef[m][0] = a0c; s_coef[m][1] = a1c; s_coef[m][2] = ap0;
        s_coef[m][3] = b0c; s_coef[m][4] = b1c; s_coef[m][5] = ap1;
    }
    __syncthreads();
    for (int p = tid; p < NUM_MODS * T_STEPS; p += 128) {   // 180 > 128: MUST be strided
        const int m = p / T_STEPS, t = p % T_STEPS;
        const float sf  = (float)t / (float)(T_STEPS - 1);  // ref: arange(T, f32)/(T-1)
        const float s2f = sf * sf;
        const double s1 = (double)sf, s2 = (double)s2f;
        s_traj[m][t][0] = s_coef[m][0] * s2 + s_coef[m][1] * s1 + s_coef[m][2];
        s_traj[m][t][1] = s_coef[m][3] * s2 + s_coef[m][4] * s1 + s_coef[m][5];
    }
    __syncthreads();

    // ---- 6a. last-timestep + best-mode (thread 0, tiny)
    if (tid == 0) {
        double best = -1e300; int lt = 0;
        for (int t = 0; t < T_STEPS; ++t) {
            const double h = s_has[t] ? 1.0 : 0.0;
            const double v = h + (0.1 * (double)t) / (double)T_STEPS;
            if (v > best) { best = v; lt = t; }
        }
        const int mask = (best > 1.0);
        const double egx = s_gtrow[lt * 2 + 0];
        const double egy = s_gtrow[lt * 2 + 1];
        double bd = 1e300; int mi = 0;
        for (int m = 0; m < NUM_MODS; ++m) {
            const double dx = s_traj[m][lt][0] - egx;
            const double dy = s_traj[m][lt][1] - egy;
            const double d = sqrt(dx * dx + dy * dy);
            if (d < bd) { bd = d; mi = m; }
        }
        s_lt = lt; s_mi = mi; s_mask = mask;
    }
    __syncthreads();

    // ---- 6b. loss terms in parallel
    if (tid < NUM_MODS) {
        const double l = (double)s_slog[tid];
        const double g = (tid == s_mi) ? 1.0 : 0.0;
        s_red[tid] = fmax(l, 0.0) - l * g + log1p(exp(-fabs(l)));
    } else if (tid < NUM_MODS + 2 * T_STEPS) {
        const int p = tid - NUM_MODS;
        const int t = p >> 1, c = p & 1;
        double v = 0.0;
        if (s_mask && s_has[t]) {
            const double diff = s_traj[s_mi][t][c] - s_gtrow[t * 2 + c];
            const double ad = fabs(diff);
            v = (ad < 1.0) ? 0.5 * diff * diff : (ad - 0.5);
        }
        s_red[NUM_MODS + p] = v;
    }
    __syncthreads();

    if (tid == 0) {
        double cls = 0.0;
        for (int m = 0; m < NUM_MODS; ++m) cls += s_red[m];
        if (!s_mask) cls = 0.0;
        double reg = 0.0;
        for (int p = 0; p < 2 * T_STEPS; ++p) reg += s_red[NUM_MODS + p];
        int nh = 0;
        for (int t = 0; t < T_STEPS; ++t) nh += (s_has[t] != 0);
        part[(size_t)a * 4 + 0] = cls;
        part[(size_t)a * 4 + 1] = reg;
        part[(size_t)a * 4 + 2] = s_mask ? 1.0 : 0.0;
        part[(size_t)a * 4 + 3] = s_mask ? (double)nh : 0.0;
    }

    // ---- 7. traj_eval gather (temp is NOT cumsum: [0, natgs[0], ..., natgs[14]])
    const double* tp = &s_traj[0][0][0];
    for (int b = 0; b < B_BATCH; ++b) {
        const int target = (b == 0) ? 0 : natgs[b - 1];
        if (target == a) {
            for (int p = tid; p < NUM_MODS * T_STEPS * 2; p += 128)
                out[2 + (size_t)b * NUM_MODS * T_STEPS * 2 + p] = (float)tp[p];
        }
    }
}

__global__ __launch_bounds__(256) void reduce_kernel(
    const double* __restrict__ part, float* __restrict__ out)
{
    __shared__ double s0[256], s1[256], s2[256], s3[256];
    const int tid = threadIdx.x;
    double c = 0, r = 0, n = 0, w = 0;
    for (int a = tid; a < N_AGENTS; a += 256) {
        c += part[(size_t)a * 4 + 0];
        r += part[(size_t)a * 4 + 1];
        n += part[(size_t)a * 4 + 2];
        w += part[(size_t)a * 4 + 3];
    }
    s0[tid] = c; s1[tid] = r; s2[tid] = n; s3[tid] = w;
    __syncthreads();
    for (int off = 128; off >= 1; off >>= 1) {
        if (tid < off) {
            s0[tid] += s0[tid + off]; s1[tid] += s1[tid + off];
            s2[tid] += s2[tid + off]; s3[tid] += s3[tid + off];
        }
        __syncthreads();
    }
    if (tid == 0) {
        out[0]    = (float)s0[0];
        out[1]    = (float)s1[0];
        out[5762] = (float)s2[0];
        out[5763] = (float)s3[0];
    }
}

extern "C" void kernel_launch(void* const* d_in, const int* in_sizes, int n_in,
                              void* d_out, int out_size, void* d_ws, size_t ws_size,
                              hipStream_t stream) {
    const float*   roi    = (const float*)d_in[0];
    const float*   anchor = (const float*)d_in[1];
    const float*   ctrs   = (const float*)d_in[2];
    const float*   feats  = (const float*)d_in[3];
    const float*   gt     = (const float*)d_in[4];
    const int*     has    = (const int*)d_in[5];
    const int*     natgs  = (const int*)d_in[6];
    float*  out  = (float*)d_out;
    double* part = (double*)d_ws;   // 2048*4 doubles = 64 KB

    agent_kernel<<<N_AGENTS, 128, 0, stream>>>(roi, anchor, ctrs, feats, gt, has, natgs, out, part);
    reduce_kernel<<<1, 256, 0, stream>>>(part, out);
}